// Round 5
// baseline (516.268 us; speedup 1.0000x reference)
//
#include <hip/hip_runtime.h>

// Fused 4-layer RNN (LSTM,LSTM,GRU,GRU, H=64) + FC head. B=2048, T=512.
// Wave-specialized LAYER PIPELINE: 256 blocks x 512 threads (8 waves).
// Tick T: waves{0,1}=LSTM0@t=T, {2,3}=LSTM1@t=T-1, {4,5}=GRU0@t=T-2,
// {6,7}=GRU1@t=T-3. States double-buffered bf16 in LDS; producer writes
// parity T&1, consumers read parity (T-1)&1; ONE barrier per tick.
// __launch_bounds__(512,1): only 1 block/CU (grid==#CU) -> VGPR budget 256,
// no spills (R4's (512,2) capped VGPR at 128 and spilled 7.4MB/dispatch).

#define TT 512
#define SR 72            // state row stride (shorts)
#define XR 68            // xs/hfin row stride (floats)

typedef __attribute__((ext_vector_type(8))) short bfrag;  // 8 bf16
typedef __attribute__((ext_vector_type(4))) float facc;   // 4 f32

#define MFMA(a,b,c) __builtin_amdgcn_mfma_f32_16x16x32_bf16((a),(b),(c),0,0,0)

__device__ __forceinline__ short f2bf(float f){
  union { float f; unsigned u; } v; v.f = f;
  return (short)((v.u + 0x7fffu + ((v.u >> 16) & 1u)) >> 16);  // RNE
}
__device__ __forceinline__ float sigm(float xx){
  return __builtin_amdgcn_rcpf(1.0f + __expf(-xx));
}
__device__ __forceinline__ float tanh_(float xx){
  return 2.0f * __builtin_amdgcn_rcpf(1.0f + __expf(-2.0f * xx)) - 1.0f;
}

__global__ __launch_bounds__(512, 1) void rnn_fused(
    const float* __restrict__ x,
    const float* __restrict__ lw_ih0, const float* __restrict__ lw_hh0,
    const float* __restrict__ lb_ih0, const float* __restrict__ lb_hh0,
    const float* __restrict__ lw_ih1, const float* __restrict__ lw_hh1,
    const float* __restrict__ lb_ih1, const float* __restrict__ lb_hh1,
    const float* __restrict__ gw_ih0, const float* __restrict__ gw_hh0,
    const float* __restrict__ gb_ih0, const float* __restrict__ gb_hh0,
    const float* __restrict__ gw_ih1, const float* __restrict__ gw_hh1,
    const float* __restrict__ gb_ih1, const float* __restrict__ gb_hh1,
    const float* __restrict__ fc_w, const float* __restrict__ fc_b,
    float* __restrict__ out)
{
  __shared__ __align__(16) short S0[2][16 * SR];  // h0 (LSTM0 out)
  __shared__ __align__(16) short S1[2][16 * SR];  // h1 (LSTM1 out)
  __shared__ __align__(16) short S2[2][16 * SR];  // h2 (GRU0 out)
  __shared__ __align__(16) short S3[2][16 * SR];  // h3 (GRU1 out)
  __shared__ float xs[8][XR];
  __shared__ float hfin[8][XR];

  const int tid = threadIdx.x;
  const int w   = tid >> 6;        // wave 0..7
  const int layer = w >> 1;        // 0..3
  const int loc   = w & 1;         // 0/1: h-dim half [loc*32, loc*32+32)
  const int l   = tid & 63;
  const int lq  = l >> 4;
  const int lc  = l & 15;
  const int kb  = lq * 8;
  const int rb0 = blockIdx.x * 8;
  const int wrbase = (4 * lq) * SR + loc * 32 + lc;  // + m*SR + q*16

  for (int i = tid; i < 16 * SR; i += 512) {
    S0[0][i] = 0; S0[1][i] = 0; S1[0][i] = 0; S1[1][i] = 0;
    S2[0][i] = 0; S2[1][i] = 0; S3[0][i] = 0; S3[1][i] = 0;
  }
  __syncthreads();

  // staged x: every 64 ticks, each wave loads its batch row's next 64 steps
  #define STAGE_X()                                         \
    if ((T & 63) == 0 && T < TT) {                          \
      xs[w][l] = x[(rb0 + w) * TT + T + l];                 \
      __syncthreads();                                      \
    }

  if (layer == 0) {
    // ================= LSTM0: t = T, K=64 (h0 only; x is scalar FMA) ========
    bfrag wf[4][2][2];           // [gate][chunk q][ktile]
    float wxs[4][2], bs[4][2];
    #pragma unroll
    for (int G = 0; G < 4; ++G)
      #pragma unroll
      for (int q = 0; q < 2; ++q) {
        const int col = G * 64 + loc * 32 + q * 16 + lc;
        #pragma unroll
        for (int kt = 0; kt < 2; ++kt) {
          bfrag f;
          #pragma unroll
          for (int j = 0; j < 8; ++j) f[j] = f2bf(lw_hh0[col * 64 + kt * 32 + kb + j]);
          wf[G][q][kt] = f;
        }
        wxs[G][q] = lw_ih0[col];
        bs[G][q]  = lb_ih0[col] + lb_hh0[col];
      }
    float c0[2][2] = {{0,0},{0,0}};
    #pragma unroll 2
    for (int T = 0; T < TT + 3; ++T) {
      const int cur = T & 1, prv = cur ^ 1;
      STAGE_X();
      if (T < TT) {
        const short* s = S0[prv];
        const bfrag a0 = *(const bfrag*)(s + lc * SR + kb);
        const bfrag a1 = *(const bfrag*)(s + lc * SR + 32 + kb);
        facc acc[4][2];
        #pragma unroll
        for (int G = 0; G < 4; ++G)
          #pragma unroll
          for (int q = 0; q < 2; ++q) {
            facc z = {0,0,0,0};
            z = MFMA(a0, wf[G][q][0], z);
            z = MFMA(a1, wf[G][q][1], z);
            acc[G][q] = z;
          }
        #pragma unroll
        for (int m = 0; m < 2; ++m) {
          const float xv = xs[2 * lq + m][T & 63];
          #pragma unroll
          for (int q = 0; q < 2; ++q) {
            const float i_ = sigm (acc[0][q][m] + xv * wxs[0][q] + bs[0][q]);
            const float f_ = sigm (acc[1][q][m] + xv * wxs[1][q] + bs[1][q]);
            const float g_ = tanh_(acc[2][q][m] + xv * wxs[2][q] + bs[2][q]);
            const float o_ = sigm (acc[3][q][m] + xv * wxs[3][q] + bs[3][q]);
            c0[q][m] = f_ * c0[q][m] + i_ * g_;
            S0[cur][wrbase + m * SR + q * 16] = f2bf(o_ * tanh_(c0[q][m]));
          }
        }
      }
      __syncthreads();
    }
  } else if (layer == 1) {
    // ================= LSTM1: t = T-1, K=128 ([h0_t | h1_{t-1}]) ============
    bfrag wxf[4][2][2], whf[4][2][2];
    float bs[4][2];
    #pragma unroll
    for (int G = 0; G < 4; ++G)
      #pragma unroll
      for (int q = 0; q < 2; ++q) {
        const int col = G * 64 + loc * 32 + q * 16 + lc;
        #pragma unroll
        for (int kt = 0; kt < 2; ++kt) {
          bfrag f0, f1;
          #pragma unroll
          for (int j = 0; j < 8; ++j) {
            const int o = col * 64 + kt * 32 + kb + j;
            f0[j] = f2bf(lw_ih1[o]);
            f1[j] = f2bf(lw_hh1[o]);
          }
          wxf[G][q][kt] = f0; whf[G][q][kt] = f1;
        }
        bs[G][q] = lb_ih1[col] + lb_hh1[col];
      }
    float c1[2][2] = {{0,0},{0,0}};
    #pragma unroll 2
    for (int T = 0; T < TT + 3; ++T) {
      const int cur = T & 1, prv = cur ^ 1;
      STAGE_X();
      if (T >= 1 && T <= TT) {
        const short* sx = S0[prv];
        const short* sh = S1[prv];
        const bfrag ax0 = *(const bfrag*)(sx + lc * SR + kb);
        const bfrag ax1 = *(const bfrag*)(sx + lc * SR + 32 + kb);
        const bfrag ah0 = *(const bfrag*)(sh + lc * SR + kb);
        const bfrag ah1 = *(const bfrag*)(sh + lc * SR + 32 + kb);
        facc acc[4][2];
        #pragma unroll
        for (int G = 0; G < 4; ++G)
          #pragma unroll
          for (int q = 0; q < 2; ++q) {
            // two independent 2-chains (x / h) -> shorter dep chain than 4
            facc z = {0,0,0,0};
            z = MFMA(ax0, wxf[G][q][0], z);
            z = MFMA(ax1, wxf[G][q][1], z);
            facc y = {0,0,0,0};
            y = MFMA(ah0, whf[G][q][0], y);
            y = MFMA(ah1, whf[G][q][1], y);
            #pragma unroll
            for (int m = 0; m < 4; ++m) z[m] += y[m];
            acc[G][q] = z;
          }
        #pragma unroll
        for (int m = 0; m < 2; ++m)
          #pragma unroll
          for (int q = 0; q < 2; ++q) {
            const float i_ = sigm (acc[0][q][m] + bs[0][q]);
            const float f_ = sigm (acc[1][q][m] + bs[1][q]);
            const float g_ = tanh_(acc[2][q][m] + bs[2][q]);
            const float o_ = sigm (acc[3][q][m] + bs[3][q]);
            c1[q][m] = f_ * c1[q][m] + i_ * g_;
            S1[cur][wrbase + m * SR + q * 16] = f2bf(o_ * tanh_(c1[q][m]));
          }
      }
      __syncthreads();
    }
  } else if (layer == 2) {
    // ================= GRU0: t = T-2 (x-part = h1_t, h-part = h2_{t-1}) =====
    bfrag gx[3][2][2], gh[3][2][2];
    float brz[2][2], bnx[2], bnh[2];
    #pragma unroll
    for (int G = 0; G < 3; ++G)
      #pragma unroll
      for (int q = 0; q < 2; ++q) {
        const int col = G * 64 + loc * 32 + q * 16 + lc;
        #pragma unroll
        for (int kt = 0; kt < 2; ++kt) {
          bfrag f0, f1;
          #pragma unroll
          for (int j = 0; j < 8; ++j) {
            const int o = col * 64 + kt * 32 + kb + j;
            f0[j] = f2bf(gw_ih0[o]);
            f1[j] = f2bf(gw_hh0[o]);
          }
          gx[G][q][kt] = f0; gh[G][q][kt] = f1;
        }
        if (G < 2) brz[G][q] = gb_ih0[col] + gb_hh0[col];
        else { bnx[q] = gb_ih0[col]; bnh[q] = gb_hh0[col]; }
      }
    float h2[2][2] = {{0,0},{0,0}};
    #pragma unroll 2
    for (int T = 0; T < TT + 3; ++T) {
      const int cur = T & 1, prv = cur ^ 1;
      STAGE_X();
      if (T >= 2 && T <= TT + 1) {
        const short* sx = S1[prv];
        const short* sh = S2[prv];
        const bfrag ax0 = *(const bfrag*)(sx + lc * SR + kb);
        const bfrag ax1 = *(const bfrag*)(sx + lc * SR + 32 + kb);
        const bfrag ah0 = *(const bfrag*)(sh + lc * SR + kb);
        const bfrag ah1 = *(const bfrag*)(sh + lc * SR + 32 + kb);
        facc ax[3][2], ah[3][2];
        #pragma unroll
        for (int G = 0; G < 3; ++G)
          #pragma unroll
          for (int q = 0; q < 2; ++q) {
            facc z = {0,0,0,0};
            z = MFMA(ax0, gx[G][q][0], z);
            z = MFMA(ax1, gx[G][q][1], z);
            ax[G][q] = z;
            facc y = {0,0,0,0};
            y = MFMA(ah0, gh[G][q][0], y);
            y = MFMA(ah1, gh[G][q][1], y);
            ah[G][q] = y;
          }
        #pragma unroll
        for (int m = 0; m < 2; ++m)
          #pragma unroll
          for (int q = 0; q < 2; ++q) {
            const float r_ = sigm (ax[0][q][m] + ah[0][q][m] + brz[0][q]);
            const float z_ = sigm (ax[1][q][m] + ah[1][q][m] + brz[1][q]);
            const float n_ = tanh_(ax[2][q][m] + bnx[q] + r_ * (ah[2][q][m] + bnh[q]));
            h2[q][m] = (1.0f - z_) * n_ + z_ * h2[q][m];
            S2[cur][wrbase + m * SR + q * 16] = f2bf(h2[q][m]);
          }
      }
      __syncthreads();
    }
  } else {
    // ================= GRU1: t = T-3 (x-part = h2_t, h-part = h3_{t-1}) =====
    bfrag gx[3][2][2], gh[3][2][2];
    float brz[2][2], bnx[2], bnh[2];
    #pragma unroll
    for (int G = 0; G < 3; ++G)
      #pragma unroll
      for (int q = 0; q < 2; ++q) {
        const int col = G * 64 + loc * 32 + q * 16 + lc;
        #pragma unroll
        for (int kt = 0; kt < 2; ++kt) {
          bfrag f0, f1;
          #pragma unroll
          for (int j = 0; j < 8; ++j) {
            const int o = col * 64 + kt * 32 + kb + j;
            f0[j] = f2bf(gw_ih1[o]);
            f1[j] = f2bf(gw_hh1[o]);
          }
          gx[G][q][kt] = f0; gh[G][q][kt] = f1;
        }
        if (G < 2) brz[G][q] = gb_ih1[col] + gb_hh1[col];
        else { bnx[q] = gb_ih1[col]; bnh[q] = gb_hh1[col]; }
      }
    float h3[2][2] = {{0,0},{0,0}};
    #pragma unroll 2
    for (int T = 0; T < TT + 3; ++T) {
      const int cur = T & 1, prv = cur ^ 1;
      STAGE_X();
      if (T >= 3) {
        const short* sx = S2[prv];
        const short* sh = S3[prv];
        const bfrag ax0 = *(const bfrag*)(sx + lc * SR + kb);
        const bfrag ax1 = *(const bfrag*)(sx + lc * SR + 32 + kb);
        const bfrag ah0 = *(const bfrag*)(sh + lc * SR + kb);
        const bfrag ah1 = *(const bfrag*)(sh + lc * SR + 32 + kb);
        facc ax[3][2], ah[3][2];
        #pragma unroll
        for (int G = 0; G < 3; ++G)
          #pragma unroll
          for (int q = 0; q < 2; ++q) {
            facc z = {0,0,0,0};
            z = MFMA(ax0, gx[G][q][0], z);
            z = MFMA(ax1, gx[G][q][1], z);
            ax[G][q] = z;
            facc y = {0,0,0,0};
            y = MFMA(ah0, gh[G][q][0], y);
            y = MFMA(ah1, gh[G][q][1], y);
            ah[G][q] = y;
          }
        #pragma unroll
        for (int m = 0; m < 2; ++m)
          #pragma unroll
          for (int q = 0; q < 2; ++q) {
            const float r_ = sigm (ax[0][q][m] + ah[0][q][m] + brz[0][q]);
            const float z_ = sigm (ax[1][q][m] + ah[1][q][m] + brz[1][q]);
            const float n_ = tanh_(ax[2][q][m] + bnx[q] + r_ * (ah[2][q][m] + bnh[q]));
            h3[q][m] = (1.0f - z_) * n_ + z_ * h3[q][m];
            S3[cur][wrbase + m * SR + q * 16] = f2bf(h3[q][m]);
          }
      }
      __syncthreads();
    }
    // final hidden state -> hfin (batch row = 2lq+m)
    #pragma unroll
    for (int m = 0; m < 2; ++m)
      #pragma unroll
      for (int q = 0; q < 2; ++q)
        hfin[2 * lq + m][loc * 32 + q * 16 + lc] = h3[q][m];
  }

  __syncthreads();
  if (tid < 8) {
    float s = fc_b[0];
    #pragma unroll 8
    for (int d = 0; d < 64; ++d) s += hfin[tid][d] * fc_w[d];
    out[rb0 + tid] = s;
  }
}

extern "C" void kernel_launch(void* const* d_in, const int* in_sizes, int n_in,
                              void* d_out, int out_size, void* d_ws, size_t ws_size,
                              hipStream_t stream) {
  const float* x      = (const float*)d_in[0];
  const float* lw_ih0 = (const float*)d_in[1];
  const float* lw_hh0 = (const float*)d_in[2];
  const float* lb_ih0 = (const float*)d_in[3];
  const float* lb_hh0 = (const float*)d_in[4];
  const float* lw_ih1 = (const float*)d_in[5];
  const float* lw_hh1 = (const float*)d_in[6];
  const float* lb_ih1 = (const float*)d_in[7];
  const float* lb_hh1 = (const float*)d_in[8];
  const float* gw_ih0 = (const float*)d_in[9];
  const float* gw_hh0 = (const float*)d_in[10];
  const float* gb_ih0 = (const float*)d_in[11];
  const float* gb_hh0 = (const float*)d_in[12];
  const float* gw_ih1 = (const float*)d_in[13];
  const float* gw_hh1 = (const float*)d_in[14];
  const float* gb_ih1 = (const float*)d_in[15];
  const float* gb_hh1 = (const float*)d_in[16];
  const float* fc_w   = (const float*)d_in[17];
  const float* fc_b   = (const float*)d_in[18];

  rnn_fused<<<dim3(2048 / 8), dim3(512), 0, stream>>>(
      x, lw_ih0, lw_hh0, lb_ih0, lb_hh0, lw_ih1, lw_hh1, lb_ih1, lb_hh1,
      gw_ih0, gw_hh0, gb_ih0, gb_hh0, gw_ih1, gw_hh1, gb_ih1, gb_hh1,
      fc_w, fc_b, (float*)d_out);
}

// Round 6
// 423.769 us; speedup vs baseline: 1.2183x; 1.2183x over previous
//
#include <hip/hip_runtime.h>

// Fused 4-layer RNN (LSTM,LSTM,GRU,GRU, H=64) + FC head. B=2048, T=512.
// Wave-specialized LAYER PIPELINE: 256 blocks x 1024 threads (16 waves,
// 4 waves/SIMD). Tick T: waves{0-3}=LSTM0@t=T, {4-7}=LSTM1@t=T-1,
// {8-11}=GRU0@t=T-2, {12-15}=GRU1@t=T-3; each wave owns a 16-dim h-chunk.
// States double-buffered bf16 in LDS; one barrier per tick.
// exp2-native activations: weights/biases pre-scaled by -log2e (sigmoid
// gates) or -2*log2e (tanh gates), folded via MFMA linearity.

#define TT 512
#define SR 72            // state row stride (shorts)
#define XR 68            // xs/hfin row stride (floats)
#define LOG2E 1.44269504f

typedef __attribute__((ext_vector_type(8))) short bfrag;  // 8 bf16
typedef __attribute__((ext_vector_type(4))) float facc;   // 4 f32

#define MFMA(a,b,c) __builtin_amdgcn_mfma_f32_16x16x32_bf16((a),(b),(c),0,0,0)

__device__ __forceinline__ short f2bf(float f){
  union { float f; unsigned u; } v; v.f = f;
  return (short)((v.u + 0x7fffu + ((v.u >> 16) & 1u)) >> 16);  // RNE
}
// u already scaled by -log2e: sigma(x) = 1/(1+2^u)
__device__ __forceinline__ float sigmP(float u){
  return __builtin_amdgcn_rcpf(1.0f + __builtin_amdgcn_exp2f(u));
}
// u already scaled by -2*log2e: tanh(x) = 2/(1+2^u) - 1
__device__ __forceinline__ float tanhP(float u){
  return 2.0f * __builtin_amdgcn_rcpf(1.0f + __builtin_amdgcn_exp2f(u)) - 1.0f;
}

__global__ __launch_bounds__(1024, 4) void rnn_fused(
    const float* __restrict__ x,
    const float* __restrict__ lw_ih0, const float* __restrict__ lw_hh0,
    const float* __restrict__ lb_ih0, const float* __restrict__ lb_hh0,
    const float* __restrict__ lw_ih1, const float* __restrict__ lw_hh1,
    const float* __restrict__ lb_ih1, const float* __restrict__ lb_hh1,
    const float* __restrict__ gw_ih0, const float* __restrict__ gw_hh0,
    const float* __restrict__ gb_ih0, const float* __restrict__ gb_hh0,
    const float* __restrict__ gw_ih1, const float* __restrict__ gw_hh1,
    const float* __restrict__ gb_ih1, const float* __restrict__ gb_hh1,
    const float* __restrict__ fc_w, const float* __restrict__ fc_b,
    float* __restrict__ out)
{
  __shared__ __align__(16) short S0[2][16 * SR];  // h0 (LSTM0 out)
  __shared__ __align__(16) short S1[2][16 * SR];  // h1 (LSTM1 out)
  __shared__ __align__(16) short S2[2][16 * SR];  // h2 (GRU0 out)
  __shared__ __align__(16) short S3[2][16 * SR];  // h3 (GRU1 out)
  __shared__ float xs[8][XR];
  __shared__ float hfin[8][XR];

  const int tid = threadIdx.x;
  const int w     = tid >> 6;      // wave 0..15
  const int layer = w >> 2;        // 0..3
  const int lo4   = w & 3;         // h-chunk [lo4*16, lo4*16+16)
  const int l   = tid & 63;
  const int lq  = l >> 4;
  const int lc  = l & 15;
  const int kb  = lq * 8;
  const int rb0 = blockIdx.x * 8;
  const int wrbase = (4 * lq) * SR + lo4 * 16 + lc;  // + m*SR

  const float SS  = -LOG2E;          // sigmoid-gate scale
  const float ST2 = -2.0f * LOG2E;   // tanh-gate scale

  for (int i = tid; i < 16 * SR; i += 1024) {
    S0[0][i] = 0; S0[1][i] = 0; S1[0][i] = 0; S1[1][i] = 0;
    S2[0][i] = 0; S2[1][i] = 0; S3[0][i] = 0; S3[1][i] = 0;
  }
  __syncthreads();

  #define STAGE_X()                                                    \
    if ((T & 63) == 0 && T < TT) {                                     \
      if (tid < 512) xs[tid >> 6][tid & 63] =                          \
          x[(rb0 + (tid >> 6)) * TT + T + (tid & 63)];                 \
      __syncthreads();                                                 \
    }

  if (layer == 0) {
    // ============ LSTM0: t = T, K=64 (h-part; x is scalar FMA) ============
    bfrag wf[4][2];
    float wxs[4], bs[4];
    #pragma unroll
    for (int G = 0; G < 4; ++G) {
      const float sc = (G == 2) ? ST2 : SS;
      const int col = G * 64 + lo4 * 16 + lc;
      #pragma unroll
      for (int kt = 0; kt < 2; ++kt) {
        bfrag f;
        #pragma unroll
        for (int j = 0; j < 8; ++j)
          f[j] = f2bf(sc * lw_hh0[col * 64 + kt * 32 + kb + j]);
        wf[G][kt] = f;
      }
      wxs[G] = sc * lw_ih0[col];
      bs[G]  = sc * (lb_ih0[col] + lb_hh0[col]);
    }
    float c0[2] = {0, 0};
    #pragma unroll 2
    for (int T = 0; T < TT + 3; ++T) {
      const int cur = T & 1, prv = cur ^ 1;
      STAGE_X();
      if (T < TT) {
        const short* s = S0[prv];
        const bfrag a0 = *(const bfrag*)(s + lc * SR + kb);
        const bfrag a1 = *(const bfrag*)(s + lc * SR + 32 + kb);
        facc acc[4];
        #pragma unroll
        for (int G = 0; G < 4; ++G) {
          facc z = {0,0,0,0};
          z = MFMA(a0, wf[G][0], z);
          z = MFMA(a1, wf[G][1], z);
          acc[G] = z;
        }
        #pragma unroll
        for (int m = 0; m < 2; ++m) {
          const float xv = xs[2 * lq + m][T & 63];
          const float i_ = sigmP(acc[0][m] + xv * wxs[0] + bs[0]);
          const float f_ = sigmP(acc[1][m] + xv * wxs[1] + bs[1]);
          const float g_ = tanhP(acc[2][m] + xv * wxs[2] + bs[2]);
          const float o_ = sigmP(acc[3][m] + xv * wxs[3] + bs[3]);
          c0[m] = f_ * c0[m] + i_ * g_;
          S0[cur][wrbase + m * SR] = f2bf(o_ * tanhP(c0[m] * ST2));
        }
      }
      __syncthreads();
    }
  } else if (layer == 1) {
    // ============ LSTM1: t = T-1, K=128 ([h0_t | h1_{t-1}]) ============
    bfrag wxf[4][2], whf[4][2];
    float bs[4];
    #pragma unroll
    for (int G = 0; G < 4; ++G) {
      const float sc = (G == 2) ? ST2 : SS;
      const int col = G * 64 + lo4 * 16 + lc;
      #pragma unroll
      for (int kt = 0; kt < 2; ++kt) {
        bfrag f0, f1;
        #pragma unroll
        for (int j = 0; j < 8; ++j) {
          const int o = col * 64 + kt * 32 + kb + j;
          f0[j] = f2bf(sc * lw_ih1[o]);
          f1[j] = f2bf(sc * lw_hh1[o]);
        }
        wxf[G][kt] = f0; whf[G][kt] = f1;
      }
      bs[G] = sc * (lb_ih1[col] + lb_hh1[col]);
    }
    float c1[2] = {0, 0};
    #pragma unroll 2
    for (int T = 0; T < TT + 3; ++T) {
      const int cur = T & 1, prv = cur ^ 1;
      STAGE_X();
      if (T >= 1 && T <= TT) {
        const short* sx = S0[prv];
        const short* sh = S1[prv];
        const bfrag ax0 = *(const bfrag*)(sx + lc * SR + kb);
        const bfrag ax1 = *(const bfrag*)(sx + lc * SR + 32 + kb);
        const bfrag ah0 = *(const bfrag*)(sh + lc * SR + kb);
        const bfrag ah1 = *(const bfrag*)(sh + lc * SR + 32 + kb);
        facc acc[4];
        #pragma unroll
        for (int G = 0; G < 4; ++G) {
          facc z = {0,0,0,0};
          z = MFMA(ax0, wxf[G][0], z);
          z = MFMA(ax1, wxf[G][1], z);
          facc y = {0,0,0,0};
          y = MFMA(ah0, whf[G][0], y);
          y = MFMA(ah1, whf[G][1], y);
          #pragma unroll
          for (int m = 0; m < 4; ++m) z[m] += y[m];
          acc[G] = z;
        }
        #pragma unroll
        for (int m = 0; m < 2; ++m) {
          const float i_ = sigmP(acc[0][m] + bs[0]);
          const float f_ = sigmP(acc[1][m] + bs[1]);
          const float g_ = tanhP(acc[2][m] + bs[2]);
          const float o_ = sigmP(acc[3][m] + bs[3]);
          c1[m] = f_ * c1[m] + i_ * g_;
          S1[cur][wrbase + m * SR] = f2bf(o_ * tanhP(c1[m] * ST2));
        }
      }
      __syncthreads();
    }
  } else if (layer == 2) {
    // ============ GRU0: t = T-2 (x-part = h1_t, h-part = h2_{t-1}) ========
    bfrag gxf[3][2], ghf[3][2];
    float brz[2], bnx, bnh;
    #pragma unroll
    for (int G = 0; G < 3; ++G) {
      const float sc = (G == 2) ? ST2 : SS;
      const int col = G * 64 + lo4 * 16 + lc;
      #pragma unroll
      for (int kt = 0; kt < 2; ++kt) {
        bfrag f0, f1;
        #pragma unroll
        for (int j = 0; j < 8; ++j) {
          const int o = col * 64 + kt * 32 + kb + j;
          f0[j] = f2bf(sc * gw_ih0[o]);
          f1[j] = f2bf(sc * gw_hh0[o]);
        }
        gxf[G][kt] = f0; ghf[G][kt] = f1;
      }
      if (G < 2) brz[G] = sc * (gb_ih0[col] + gb_hh0[col]);
      else { bnx = sc * gb_ih0[col]; bnh = sc * gb_hh0[col]; }
    }
    float h2[2] = {0, 0};
    #pragma unroll 2
    for (int T = 0; T < TT + 3; ++T) {
      const int cur = T & 1, prv = cur ^ 1;
      STAGE_X();
      if (T >= 2 && T <= TT + 1) {
        const short* sx = S1[prv];
        const short* sh = S2[prv];
        const bfrag ax0 = *(const bfrag*)(sx + lc * SR + kb);
        const bfrag ax1 = *(const bfrag*)(sx + lc * SR + 32 + kb);
        const bfrag ah0 = *(const bfrag*)(sh + lc * SR + kb);
        const bfrag ah1 = *(const bfrag*)(sh + lc * SR + 32 + kb);
        facc ax[3], ah[3];
        #pragma unroll
        for (int G = 0; G < 3; ++G) {
          facc z = {0,0,0,0};
          z = MFMA(ax0, gxf[G][0], z);
          z = MFMA(ax1, gxf[G][1], z);
          ax[G] = z;
          facc y = {0,0,0,0};
          y = MFMA(ah0, ghf[G][0], y);
          y = MFMA(ah1, ghf[G][1], y);
          ah[G] = y;
        }
        #pragma unroll
        for (int m = 0; m < 2; ++m) {
          const float r_ = sigmP(ax[0][m] + ah[0][m] + brz[0]);
          const float z_ = sigmP(ax[1][m] + ah[1][m] + brz[1]);
          const float n_ = tanhP((ax[2][m] + bnx) + r_ * (ah[2][m] + bnh));
          h2[m] = n_ + z_ * (h2[m] - n_);
          S2[cur][wrbase + m * SR] = f2bf(h2[m]);
        }
      }
      __syncthreads();
    }
  } else {
    // ============ GRU1: t = T-3 (x-part = h2_t, h-part = h3_{t-1}) ========
    bfrag gxf[3][2], ghf[3][2];
    float brz[2], bnx, bnh;
    #pragma unroll
    for (int G = 0; G < 3; ++G) {
      const float sc = (G == 2) ? ST2 : SS;
      const int col = G * 64 + lo4 * 16 + lc;
      #pragma unroll
      for (int kt = 0; kt < 2; ++kt) {
        bfrag f0, f1;
        #pragma unroll
        for (int j = 0; j < 8; ++j) {
          const int o = col * 64 + kt * 32 + kb + j;
          f0[j] = f2bf(sc * gw_ih1[o]);
          f1[j] = f2bf(sc * gw_hh1[o]);
        }
        gxf[G][kt] = f0; ghf[G][kt] = f1;
      }
      if (G < 2) brz[G] = sc * (gb_ih1[col] + gb_hh1[col]);
      else { bnx = sc * gb_ih1[col]; bnh = sc * gb_hh1[col]; }
    }
    float h3[2] = {0, 0};
    #pragma unroll 2
    for (int T = 0; T < TT + 3; ++T) {
      const int cur = T & 1, prv = cur ^ 1;
      STAGE_X();
      if (T >= 3) {
        const short* sx = S2[prv];
        const short* sh = S3[prv];
        const bfrag ax0 = *(const bfrag*)(sx + lc * SR + kb);
        const bfrag ax1 = *(const bfrag*)(sx + lc * SR + 32 + kb);
        const bfrag ah0 = *(const bfrag*)(sh + lc * SR + kb);
        const bfrag ah1 = *(const bfrag*)(sh + lc * SR + 32 + kb);
        facc ax[3], ah[3];
        #pragma unroll
        for (int G = 0; G < 3; ++G) {
          facc z = {0,0,0,0};
          z = MFMA(ax0, gxf[G][0], z);
          z = MFMA(ax1, gxf[G][1], z);
          ax[G] = z;
          facc y = {0,0,0,0};
          y = MFMA(ah0, ghf[G][0], y);
          y = MFMA(ah1, ghf[G][1], y);
          ah[G] = y;
        }
        #pragma unroll
        for (int m = 0; m < 2; ++m) {
          const float r_ = sigmP(ax[0][m] + ah[0][m] + brz[0]);
          const float z_ = sigmP(ax[1][m] + ah[1][m] + brz[1]);
          const float n_ = tanhP((ax[2][m] + bnx) + r_ * (ah[2][m] + bnh));
          h3[m] = n_ + z_ * (h3[m] - n_);
          S3[cur][wrbase + m * SR] = f2bf(h3[m]);
        }
      }
      __syncthreads();
    }
    // final hidden state -> hfin (batch row = 2lq+m)
    #pragma unroll
    for (int m = 0; m < 2; ++m)
      hfin[2 * lq + m][lo4 * 16 + lc] = h3[m];
  }

  __syncthreads();
  if (tid < 8) {
    float s = fc_b[0];
    #pragma unroll 8
    for (int d = 0; d < 64; ++d) s += hfin[tid][d] * fc_w[d];
    out[rb0 + tid] = s;
  }
}

extern "C" void kernel_launch(void* const* d_in, const int* in_sizes, int n_in,
                              void* d_out, int out_size, void* d_ws, size_t ws_size,
                              hipStream_t stream) {
  const float* x      = (const float*)d_in[0];
  const float* lw_ih0 = (const float*)d_in[1];
  const float* lw_hh0 = (const float*)d_in[2];
  const float* lb_ih0 = (const float*)d_in[3];
  const float* lb_hh0 = (const float*)d_in[4];
  const float* lw_ih1 = (const float*)d_in[5];
  const float* lw_hh1 = (const float*)d_in[6];
  const float* lb_ih1 = (const float*)d_in[7];
  const float* lb_hh1 = (const float*)d_in[8];
  const float* gw_ih0 = (const float*)d_in[9];
  const float* gw_hh0 = (const float*)d_in[10];
  const float* gb_ih0 = (const float*)d_in[11];
  const float* gb_hh0 = (const float*)d_in[12];
  const float* gw_ih1 = (const float*)d_in[13];
  const float* gw_hh1 = (const float*)d_in[14];
  const float* gb_ih1 = (const float*)d_in[15];
  const float* gb_hh1 = (const float*)d_in[16];
  const float* fc_w   = (const float*)d_in[17];
  const float* fc_b   = (const float*)d_in[18];

  rnn_fused<<<dim3(2048 / 8), dim3(1024), 0, stream>>>(
      x, lw_ih0, lw_hh0, lb_ih0, lb_hh0, lw_ih1, lw_hh1, lb_ih1, lb_hh1,
      gw_ih0, gw_hh0, gb_ih0, gb_hh0, gw_ih1, gw_hh1, gb_ih1, gb_hh1,
      fc_w, fc_b, (float*)d_out);
}